// Round 3
// baseline (1397.486 us; speedup 1.0000x reference)
//
#include <hip/hip_runtime.h>

typedef short s8v __attribute__((ext_vector_type(8)));
typedef float f4v __attribute__((ext_vector_type(4)));

#define DIM 1024
#define LSEQ 8192
#define NH 16
#define HD 64

__device__ __forceinline__ unsigned short f2bf(float x) {
  unsigned int u = __float_as_uint(x);
  u = (u + 0x7FFFu + ((u >> 16) & 1u)) >> 16;
  return (unsigned short)u;
}
__device__ __forceinline__ float bf2f(unsigned short u) {
  return __uint_as_float(((unsigned int)u) << 16);
}

// ---------------------------------------------------------------- utilities
__global__ void k_zero(float* __restrict__ p, int n) {
  int i = blockIdx.x * 256 + threadIdx.x;
  if (i < n) p[i] = 0.f;
}

__global__ void k_detect_pad(const unsigned int* __restrict__ pad, int* __restrict__ flag) {
  int t = threadIdx.x;
  int bad = 0;
#pragma unroll
  for (int q = 0; q < 4; ++q) {
    unsigned v = pad[t * 4 + q];
    if (v > 1u) bad = 1;
  }
  if (bad) *flag = 1;
}

// transpose n x n fp32 -> bf16 (dst[j][i] = src[i][j])
__global__ void k_transpose_bf16(const float* __restrict__ src, unsigned short* __restrict__ dst, int n) {
  __shared__ unsigned short tile[64][65];
  int t = threadIdx.x;
  int i0 = blockIdx.y * 64, j0 = blockIdx.x * 64;
  int isub = t >> 4, jseg = (t & 15) * 4;
#pragma unroll
  for (int q = 0; q < 4; ++q) {
    int i = isub + q * 16;
    const float4 v = *(const float4*)(src + (size_t)(i0 + i) * n + j0 + jseg);
    tile[jseg + 0][i] = f2bf(v.x);
    tile[jseg + 1][i] = f2bf(v.y);
    tile[jseg + 2][i] = f2bf(v.z);
    tile[jseg + 3][i] = f2bf(v.w);
  }
  __syncthreads();
  int r = t >> 2, seg = t & 3;
  unsigned short* dp = dst + (size_t)(j0 + r) * n + i0 + seg * 16;
#pragma unroll
  for (int k = 0; k < 16; ++k) dp[k] = tile[r][seg * 16 + k];
}

// Qp[b][n] = (Q[b] @ Wq + bq)[n] * (1/sqrt(HD))
__global__ __launch_bounds__(256) void k_qproj(const float* __restrict__ Q, const float* __restrict__ Wq,
                                               const float* __restrict__ bq, float* __restrict__ Qp) {
  int b = blockIdx.x, t = threadIdx.x;
  __shared__ float qs[DIM];
  for (int i = t; i < DIM; i += 256) qs[i] = Q[b * DIM + i];
  __syncthreads();
  float acc[4];
#pragma unroll
  for (int q = 0; q < 4; ++q) acc[q] = bq[t + q * 256];
  for (int d = 0; d < DIM; ++d) {
    float qd = qs[d];
#pragma unroll
    for (int q = 0; q < 4; ++q) acc[q] += qd * Wq[(size_t)d * DIM + t + q * 256];
  }
#pragma unroll
  for (int q = 0; q < 4; ++q) Qp[b * DIM + t + q * 256] = acc[q] * 0.125f;
}

// ---------------------------------------------------------------- GEMM core
struct SMemStage {
  unsigned short a[128 * 32];
  unsigned short b[128 * 32];
};

__device__ __forceinline__ void gemm_mainloop(const float* __restrict__ gA_base,
                                              const unsigned short* __restrict__ gB_base,
                                              unsigned short* a_lds, unsigned short* b_lds,
                                              int t, f4v acc[4][4]) {
  const int lane = t & 63, w = t >> 6;
  const int ln = lane & 15, kq = lane >> 4;
  const int wr = w >> 1, wc = w & 1;
  const int srow = t >> 1, sseg = t & 1;
  const float* gA = gA_base + (size_t)srow * DIM + sseg * 16;
  const unsigned short* gB = gB_base + (size_t)srow * DIM + sseg * 16;

  for (int kt = 0; kt < 32; ++kt) {
    const float4* pa = (const float4*)(gA + kt * 32);
    float4 f0 = pa[0], f1 = pa[1], f2 = pa[2], f3 = pa[3];
    const uint4* pb = (const uint4*)(gB + kt * 32);
    uint4 ub0 = pb[0], ub1 = pb[1];
    __syncthreads();  // previous iteration's LDS reads complete
    s8v av0, av1;
    av0[0] = (short)f2bf(f0.x); av0[1] = (short)f2bf(f0.y);
    av0[2] = (short)f2bf(f0.z); av0[3] = (short)f2bf(f0.w);
    av0[4] = (short)f2bf(f1.x); av0[5] = (short)f2bf(f1.y);
    av0[6] = (short)f2bf(f1.z); av0[7] = (short)f2bf(f1.w);
    av1[0] = (short)f2bf(f2.x); av1[1] = (short)f2bf(f2.y);
    av1[2] = (short)f2bf(f2.z); av1[3] = (short)f2bf(f2.w);
    av1[4] = (short)f2bf(f3.x); av1[5] = (short)f2bf(f3.y);
    av1[6] = (short)f2bf(f3.z); av1[7] = (short)f2bf(f3.w);
    *(s8v*)&a_lds[srow * 32 + sseg * 16] = av0;
    *(s8v*)&a_lds[srow * 32 + sseg * 16 + 8] = av1;
    *(uint4*)&b_lds[srow * 32 + sseg * 16] = ub0;
    *(uint4*)&b_lds[srow * 32 + sseg * 16 + 8] = ub1;
    __syncthreads();
    s8v aF[4], bF[4];
#pragma unroll
    for (int m = 0; m < 4; ++m) aF[m] = *(const s8v*)&a_lds[(wr * 64 + m * 16 + ln) * 32 + kq * 8];
#pragma unroll
    for (int n = 0; n < 4; ++n) bF[n] = *(const s8v*)&b_lds[(wc * 64 + n * 16 + ln) * 32 + kq * 8];
#pragma unroll
    for (int m = 0; m < 4; ++m)
#pragma unroll
      for (int n = 0; n < 4; ++n)
        acc[m][n] = __builtin_amdgcn_mfma_f32_16x16x32_bf16(aF[m], bF[n], acc[m][n], 0, 0, 0);
  }
}

// ------------------------------------------------------- K-projection kernel
struct SMemEpiK {
  float qp[128];                 // [2 heads][64]
  unsigned short pp1t[64 * 72];  // pp1_w^T bf16, padded stride 72
  float plg[64], plb[64], p2w[64], pb1[64];
};
union KUnion { SMemStage s; SMemEpiK e; };

__global__ __launch_bounds__(256) void k_gemm_k(
    const float* __restrict__ K, const unsigned short* __restrict__ WkT,
    const float* __restrict__ bk, const float* __restrict__ Qp,
    const float* __restrict__ eps, const int* __restrict__ padding,
    const int* __restrict__ padflag, const unsigned short* __restrict__ pp1T,
    const float* __restrict__ pp1b, const float* __restrict__ plng,
    const float* __restrict__ plnb, const float* __restrict__ pp2w,
    const float* __restrict__ pp2b, float* __restrict__ num_ws,
    float* __restrict__ wsum, float* __restrict__ prior_out) {
  __shared__ unsigned short kp[128 * 136];  // padded stride 136 (272 B, odd 16B-chunks)
  __shared__ KUnion u;

  const int t = threadIdx.x;
  const int lane = t & 63, w = t >> 6;
  const int ln = lane & 15, kq = lane >> 4;
  const int wr = w >> 1, wc = w & 1;
  const int rt = blockIdx.x;  // 0..511 row tiles
  const int by = blockIdx.y;  // 0..7 col tiles
  const int b = rt >> 6, ltile = rt & 63;
  const int n0 = by * 128;

  f4v acc[4][4];
#pragma unroll
  for (int m = 0; m < 4; ++m)
#pragma unroll
    for (int n = 0; n < 4; ++n) acc[m][n] = (f4v){0.f, 0.f, 0.f, 0.f};

  gemm_mainloop(K + (size_t)rt * 128 * DIM, WkT + (size_t)n0 * DIM, u.s.a, u.s.b, t, acc);
  __syncthreads();

  // ---- epilogue phase 1: bias + bf16 Kp tile to LDS, stage small operands
  {
    float bkv[4];
#pragma unroll
    for (int n = 0; n < 4; ++n) bkv[n] = bk[n0 + wc * 64 + n * 16 + ln];
#pragma unroll
    for (int m = 0; m < 4; ++m)
#pragma unroll
      for (int n = 0; n < 4; ++n)
#pragma unroll
        for (int j = 0; j < 4; ++j) {
          int row = wr * 64 + m * 16 + kq * 4 + j;
          int col = wc * 64 + n * 16 + ln;
          kp[row * 136 + col] = f2bf(acc[m][n][j] + bkv[n]);
        }
  }
  if (t < 128) u.e.qp[t] = Qp[b * DIM + by * 128 + t];
  {
    int r = t >> 2, sg = t & 3;
    const unsigned short* sp = pp1T + r * 64 + sg * 16;
    unsigned short* dp = &u.e.pp1t[r * 72 + sg * 16];
    *(uint4*)dp = *(const uint4*)sp;
    *(uint4*)(dp + 8) = *(const uint4*)(sp + 8);
  }
  if (t < 64) {
    u.e.plg[t] = plng[t];
    u.e.plb[t] = plnb[t];
    u.e.p2w[t] = pp2w[t];
    u.e.pb1[t] = pp1b[t];
  }
  __syncthreads();

  // ---- phi / num / wsum
  {
    const int l_loc = t & 127, h_loc = t >> 7;
    const int hg = by * 2 + h_loc;
    const int l_glob = ltile * 128 + l_loc;
    const unsigned short* kr = &kp[l_loc * 136 + h_loc * 64];
    float ph = 0.f;
#pragma unroll
    for (int s = 0; s < 8; ++s) {
      s8v kv = *(const s8v*)&kr[s * 8];
#pragma unroll
      for (int j = 0; j < 8; ++j) ph += bf2f((unsigned short)kv[j]) * u.e.qp[h_loc * 64 + s * 8 + j];
    }
    float ev = eps[(size_t)(b * NH + hg) * LSEQ + l_glob];
    const int pf = *padflag;
    int pd = pf ? (int)((const unsigned char*)padding)[(size_t)b * LSEQ + l_glob]
                : padding[(size_t)b * LSEQ + l_glob];
    float sv = __expf(ph - 0.03125f + 0.25f * ev);
    float numv = pd ? 0.f : sv * sv;
    num_ws[(size_t)(b * NH + hg) * LSEQ + l_glob] = numv;
    float wsl = numv;
#pragma unroll
    for (int m = 1; m < 64; m <<= 1) wsl += __shfl_xor(wsl, m);
    if (lane == 0) atomicAdd(&wsum[b * NH + hg], wsl);
  }

  // ---- prior branch: h = relu(LN(Kp @ pp1_w + pp1_b)); prior_phi = h . pp2w
  {
    f4v hacc[4][4];
#pragma unroll
    for (int m = 0; m < 4; ++m)
#pragma unroll
      for (int n = 0; n < 4; ++n) hacc[m][n] = (f4v){0.f, 0.f, 0.f, 0.f};
#pragma unroll
    for (int ks = 0; ks < 2; ++ks) {
      s8v a3[4], b3[4];
#pragma unroll
      for (int mm = 0; mm < 4; ++mm) {
        int r2 = w * 64 + mm * 16 + ln;  // virtual row: h*128 + l
        int l2 = r2 & 127, h2 = r2 >> 7;
        a3[mm] = *(const s8v*)&kp[l2 * 136 + h2 * 64 + ks * 32 + kq * 8];
      }
#pragma unroll
      for (int nn = 0; nn < 4; ++nn)
        b3[nn] = *(const s8v*)&u.e.pp1t[(nn * 16 + ln) * 72 + ks * 32 + kq * 8];
#pragma unroll
      for (int mm = 0; mm < 4; ++mm)
#pragma unroll
        for (int nn = 0; nn < 4; ++nn)
          hacc[mm][nn] = __builtin_amdgcn_mfma_f32_16x16x32_bf16(a3[mm], b3[nn], hacc[mm][nn], 0, 0, 0);
    }
    float plgv[4], plbv[4], p2wv[4], pb1v[4];
#pragma unroll
    for (int nn = 0; nn < 4; ++nn) {
      int e = nn * 16 + ln;
      plgv[nn] = u.e.plg[e]; plbv[nn] = u.e.plb[e];
      p2wv[nn] = u.e.p2w[e]; pb1v[nn] = u.e.pb1[e];
    }
    float p2b = pp2b[0];
#pragma unroll
    for (int mm = 0; mm < 4; ++mm)
#pragma unroll
      for (int j = 0; j < 4; ++j) {
        float x[4];
        float s1 = 0.f, s2 = 0.f;
#pragma unroll
        for (int nn = 0; nn < 4; ++nn) {
          x[nn] = hacc[mm][nn][j] + pb1v[nn];
          s1 += x[nn]; s2 += x[nn] * x[nn];
        }
#pragma unroll
        for (int m2 = 1; m2 < 16; m2 <<= 1) { s1 += __shfl_xor(s1, m2); s2 += __shfl_xor(s2, m2); }
        float mean = s1 * (1.f / 64.f);
        float var = s2 * (1.f / 64.f) - mean * mean;
        float rs = rsqrtf(var + 1e-5f);
        float pp = 0.f;
#pragma unroll
        for (int nn = 0; nn < 4; ++nn) {
          float hh = (x[nn] - mean) * rs * plgv[nn] + plbv[nn];
          pp += fmaxf(hh, 0.f) * p2wv[nn];
        }
#pragma unroll
        for (int m2 = 1; m2 < 16; m2 <<= 1) pp += __shfl_xor(pp, m2);
        if (ln == 0) {
          int r2 = w * 64 + mm * 16 + kq * 4 + j;
          int l2 = r2 & 127, h2 = r2 >> 7;
          prior_out[(size_t)(b * NH + by * 2 + h2) * LSEQ + ltile * 128 + l2] = pp + p2b - 0.03125f;
        }
      }
  }
}

// ------------------------------------------------------- V-projection kernel
__global__ __launch_bounds__(256) void k_gemm_v(
    const float* __restrict__ V, const unsigned short* __restrict__ WvT,
    const float* __restrict__ bv, const float* __restrict__ num_ws,
    float* __restrict__ ctx_un) {
  __shared__ unsigned short vp[128 * 136];
  __shared__ union { SMemStage s; float num[256]; } u;

  const int t = threadIdx.x;
  const int lane = t & 63, w = t >> 6;
  const int ln = lane & 15, kq = lane >> 4;
  const int wr = w >> 1, wc = w & 1;
  const int rt = blockIdx.x;
  const int by = blockIdx.y;
  const int b = rt >> 6, ltile = rt & 63;
  const int n0 = by * 128;

  f4v acc[4][4];
#pragma unroll
  for (int m = 0; m < 4; ++m)
#pragma unroll
    for (int n = 0; n < 4; ++n) acc[m][n] = (f4v){0.f, 0.f, 0.f, 0.f};

  gemm_mainloop(V + (size_t)rt * 128 * DIM, WvT + (size_t)n0 * DIM, u.s.a, u.s.b, t, acc);
  __syncthreads();

  {
    float bvv[4];
#pragma unroll
    for (int n = 0; n < 4; ++n) bvv[n] = bv[n0 + wc * 64 + n * 16 + ln];
#pragma unroll
    for (int m = 0; m < 4; ++m)
#pragma unroll
      for (int n = 0; n < 4; ++n)
#pragma unroll
        for (int j = 0; j < 4; ++j) {
          int row = wr * 64 + m * 16 + kq * 4 + j;
          int col = wc * 64 + n * 16 + ln;
          vp[row * 136 + col] = f2bf(acc[m][n][j] + bvv[n]);
        }
  }
  {
    int h_loc = t >> 7, l_loc = t & 127;
    u.num[t] = num_ws[(size_t)(b * NH + by * 2 + h_loc) * LSEQ + ltile * 128 + l_loc];
  }
  __syncthreads();

  {
    const int n_loc = t & 127, half = t >> 7;
    const float* ns = &u.num[(n_loc >> 6) * 128 + half * 64];
    float a = 0.f;
#pragma unroll 8
    for (int li = 0; li < 64; ++li) a += bf2f(vp[(half * 64 + li) * 136 + n_loc]) * ns[li];
    atomicAdd(&ctx_un[b * DIM + n0 + n_loc], a);
  }
}

// ------------------------------------------------------------- finalization
__global__ __launch_bounds__(256) void k_final(
    const float* __restrict__ ctx_un, const float* __restrict__ wsum,
    const float* __restrict__ Wo, const float* __restrict__ bo,
    const float* __restrict__ lng, const float* __restrict__ lnb,
    const float* __restrict__ Q, float* __restrict__ out) {
  int b = blockIdx.x, t = threadIdx.x;
  __shared__ float cs[DIM];
  __shared__ float red[32];
#pragma unroll
  for (int q = 0; q < 4; ++q) {
    int n = t + q * 256;
    float wt = wsum[b * NH + (n >> 6)] + 1e-8f;
    float sc = sqrtf(rsqrtf(wt));  // wt^(-1/4)
    cs[n] = ctx_un[b * DIM + n] * sc;
  }
  __syncthreads();
  float y[4];
#pragma unroll
  for (int q = 0; q < 4; ++q) y[q] = bo[t + q * 256];
  for (int d = 0; d < DIM; ++d) {
    float cd = cs[d];
#pragma unroll
    for (int q = 0; q < 4; ++q) y[q] += cd * Wo[(size_t)d * DIM + t + q * 256];
  }
  float s1 = 0.f, s2 = 0.f;
#pragma unroll
  for (int q = 0; q < 4; ++q) { s1 += y[q]; s2 += y[q] * y[q]; }
#pragma unroll
  for (int m = 1; m < 64; m <<= 1) { s1 += __shfl_xor(s1, m); s2 += __shfl_xor(s2, m); }
  int w = t >> 6, lane = t & 63;
  if (lane == 0) { red[w] = s1; red[8 + w] = s2; }
  __syncthreads();
  float S1 = red[0] + red[1] + red[2] + red[3];
  float S2 = red[8] + red[9] + red[10] + red[11];
  float mean = S1 * (1.f / 1024.f);
  float var = S2 * (1.f / 1024.f) - mean * mean;
  float rs = rsqrtf(var + 1e-5f);
#pragma unroll
  for (int q = 0; q < 4; ++q) {
    int n = t + q * 256;
    out[b * DIM + n] = (y[q] - mean) * rs * lng[n] + lnb[n] + Q[b * DIM + n];
  }
}

// ---------------------------------------------------------------------------
extern "C" void kernel_launch(void* const* d_in, const int* in_sizes, int n_in,
                              void* d_out, int out_size, void* d_ws, size_t ws_size,
                              hipStream_t stream) {
  const float* Q = (const float*)d_in[0];
  const float* K = (const float*)d_in[1];
  const float* V = (const float*)d_in[2];
  const int* padding = (const int*)d_in[3];
  const float* eps = (const float*)d_in[4];
  const float* Wq = (const float*)d_in[5];
  const float* bq = (const float*)d_in[6];
  const float* Wk = (const float*)d_in[7];
  const float* bk = (const float*)d_in[8];
  const float* Wv = (const float*)d_in[9];
  const float* bv = (const float*)d_in[10];
  const float* Wo = (const float*)d_in[11];
  const float* bo = (const float*)d_in[12];
  const float* lng = (const float*)d_in[13];
  const float* lnb = (const float*)d_in[14];
  const float* pp1w = (const float*)d_in[15];
  const float* pp1b = (const float*)d_in[16];
  const float* plng = (const float*)d_in[17];
  const float* plnb = (const float*)d_in[18];
  const float* pp2w = (const float*)d_in[19];
  const float* pp2b = (const float*)d_in[20];

  unsigned short* WkT = (unsigned short*)d_ws;        // 2 MB
  unsigned short* WvT = WkT + (1u << 20);             // 2 MB
  unsigned short* pp1T = WvT + (1u << 20);            // 16 KB slot
  float* Qp = (float*)(pp1T + 8192);                  // 32 KB
  float* numw = Qp + 8 * DIM;                         // 4 MB
  float* wsum = numw + (size_t)8 * NH * LSEQ;         // 512 B
  float* ctxu = wsum + 128;                           // 32 KB
  int* padflag = (int*)(ctxu + 8192);

  float* outF = (float*)d_out;
  float* prior = outF + 8 * DIM;

  k_zero<<<dim3(33), 256, 0, stream>>>(wsum, 128 + 8192 + 1);
  k_detect_pad<<<dim3(1), 256, 0, stream>>>((const unsigned int*)padding, padflag);
  k_transpose_bf16<<<dim3(16, 16), 256, 0, stream>>>(Wk, WkT, 1024);
  k_transpose_bf16<<<dim3(16, 16), 256, 0, stream>>>(Wv, WvT, 1024);
  k_transpose_bf16<<<dim3(1, 1), 256, 0, stream>>>(pp1w, pp1T, 64);
  k_qproj<<<dim3(8), 256, 0, stream>>>(Q, Wq, bq, Qp);
  k_gemm_k<<<dim3(512, 8), 256, 0, stream>>>(K, WkT, bk, Qp, eps, padding, padflag,
                                             pp1T, pp1b, plng, plnb, pp2w, pp2b,
                                             numw, wsum, prior);
  k_gemm_v<<<dim3(512, 8), 256, 0, stream>>>(V, WvT, bv, numw, ctxu);
  k_final<<<dim3(8), 256, 0, stream>>>(ctxu, wsum, Wo, bo, lng, lnb, Q, outF);
}